// Round 13
// baseline (270.938 us; speedup 1.0000x reference)
//
#include <hip/hip_runtime.h>
#include <stdint.h>

#define T_TOK 4096
#define Hd    1024
#define Id    512
#define NE    16
#define NSLOT 32
#define TOPK  4
#define ECAP  1024
#define MAXT  (NE * (ECAP/128))

typedef __bf16 bf16x8 __attribute__((ext_vector_type(8)));
typedef float  floatx4 __attribute__((ext_vector_type(4)));

#define WAIT_VM(n) asm volatile("s_waitcnt vmcnt(" #n ")" ::: "memory")

static __device__ __forceinline__ void wg_barrier(){
  asm volatile("" ::: "memory");
  __builtin_amdgcn_s_barrier();
  asm volatile("" ::: "memory");
}

static __device__ __forceinline__ unsigned short f2bf(float f){
  unsigned int u = __float_as_uint(f);
  u = u + 0x7fffu + ((u >> 16) & 1u);
  return (unsigned short)(u >> 16);
}

static __device__ __forceinline__ float bf2f(unsigned short u){
  return __uint_as_float((unsigned int)u << 16);
}

// bf16(hi_src) << 16 | bf16(lo_src), truncation rounding (hi halves via v_perm)
static __device__ __forceinline__ uint32_t bfpack(uint32_t hi_src, uint32_t lo_src){
  return __builtin_amdgcn_perm(hi_src, lo_src, 0x07060302u);
}

static __device__ __forceinline__ void load_lds16(const void* g, void* l){
  __builtin_amdgcn_global_load_lds((const __attribute__((address_space(1))) void*)g,
                                   (__attribute__((address_space(3))) void*)l, 16, 0, 0);
}

// ---------------- router: logits (8 tok x 8 slots per wave) + fused x->bf16 --------------
// R4: wave-per-token was latency-bound; 8tok x 8slot amortizes rw. R10: do NOT fuse with
// transpose (zero overlap, 140 VGPR coupling).
__global__ __launch_bounds__(256) void router_kernel(
    const float* __restrict__ x, const float* __restrict__ rw,
    unsigned short* __restrict__ xb, float* __restrict__ logits,
    int* __restrict__ cursors){
  const int tid = threadIdx.x;
  if (blockIdx.x == 0 && tid < NE) cursors[tid] = 0;
  const int lane = tid & 63, sg = tid >> 6;       // sg = slot group 0..3
  const int t0 = blockIdx.x * 8;
  const int l4 = lane * 4;

  float v[64];                                     // v[t*8+s], s within group
  #pragma unroll
  for (int i = 0; i < 64; ++i) v[i] = 0.f;

  #pragma unroll
  for (int c = 0; c < 4; ++c){
    const int h = c * 256 + l4;
    float4 xv[8];
    #pragma unroll
    for (int t = 0; t < 8; ++t)
      xv[t] = *(const float4*)(x + (size_t)(t0 + t) * Hd + h);
    if (sg == 0){
      #pragma unroll
      for (int t = 0; t < 8; ++t){
        ushort4 o;
        o.x = f2bf(xv[t].x); o.y = f2bf(xv[t].y);
        o.z = f2bf(xv[t].z); o.w = f2bf(xv[t].w);
        *(ushort4*)(xb + (size_t)(t0 + t) * Hd + h) = o;
      }
    }
    #pragma unroll
    for (int s = 0; s < 8; ++s){
      float4 rv = *(const float4*)(rw + (size_t)(sg * 8 + s) * Hd + h);
      #pragma unroll
      for (int t = 0; t < 8; ++t)
        v[t*8 + s] += xv[t].x*rv.x + xv[t].y*rv.y + xv[t].z*rv.z + xv[t].w*rv.w;
    }
  }

  // merging butterfly: after bit `off`, v[i] (i % 2off == 0) holds value
  // (i | (lane & (2off-1))) summed over lane-groups of size 2off.
  #pragma unroll
  for (int off = 1; off < 64; off <<= 1){
    #pragma unroll
    for (int i = 0; i < 64; i += 2*off){
      const int j = i + off;
      float send  = (lane & off) ? v[i] : v[j];
      float other = __shfl_xor(send, off);
      v[i] = ((lane & off) ? v[j] : v[i]) + other;
    }
  }
  // v[0] on lane l = full sum of flat index l: t = l>>3, s = l&7
  logits[(size_t)(t0 + (lane >> 3)) * NSLOT + sg * 8 + (lane & 7)] = v[0];
}

// ---------------- weight transpose: register-only 128x64 tiles ----------------
// At its streaming plateau (~3.3 TB/s logical; R9 store-widening was a null; rate is
// occupancy- and pattern-insensitive). Do not iterate further.
__global__ __launch_bounds__(256) void transpose_kernel(
    const float* __restrict__ wg, const float* __restrict__ wu,
    const float* __restrict__ wd,
    unsigned short* __restrict__ wgb, unsigned short* __restrict__ wub,
    unsigned short* __restrict__ wdb){
  const int tb = blockIdx.x;                // 0..3071
  const int tid = threadIdx.x;
  const float* src; unsigned short* dst; int R, C, rt, ct;
  const int arr = tb >> 10;                 // 0:wg 1:wu 2:wd (1024 tiles each)
  const int rem = tb & 1023;
  const int e  = rem >> 6;                  // 64 tiles/expert
  const int t2 = rem & 63;
  if (arr == 0)      { src = wg; dst = wgb; R = Hd; C = Id; rt = t2 >> 3; ct = t2 & 7;  }
  else if (arr == 1) { src = wu; dst = wub; R = Hd; C = Id; rt = t2 >> 3; ct = t2 & 7;  }
  else               { src = wd; dst = wdb; R = Id; C = Hd; rt = t2 >> 4; ct = t2 & 15; }
  const int r0 = rt * 128, c0 = ct * 64;
  const float* s = src + (size_t)e * R * C;
  unsigned short* d = dst + (size_t)e * R * C;
  const int r_idx = tid >> 4;               // 16 r-blocks x 8 rows = 128 rows
  const int c_idx = tid & 15;               // 16 c-blocks x 4 cols = 64 cols
  const int rr = r0 + r_idx * 8;
  const int cc = c0 + c_idx * 4;
  uint4 u[8];
  #pragma unroll
  for (int p = 0; p < 8; ++p)
    u[p] = *(const uint4*)(s + (size_t)(rr + p)*C + cc);
  uint4 o;
  o.x = bfpack(u[1].x, u[0].x); o.y = bfpack(u[3].x, u[2].x);
  o.z = bfpack(u[5].x, u[4].x); o.w = bfpack(u[7].x, u[6].x);
  *(uint4*)(d + (size_t)(cc + 0)*R + rr) = o;
  o.x = bfpack(u[1].y, u[0].y); o.y = bfpack(u[3].y, u[2].y);
  o.z = bfpack(u[5].y, u[4].y); o.w = bfpack(u[7].y, u[6].y);
  *(uint4*)(d + (size_t)(cc + 1)*R + rr) = o;
  o.x = bfpack(u[1].z, u[0].z); o.y = bfpack(u[3].z, u[2].z);
  o.z = bfpack(u[5].z, u[4].z); o.w = bfpack(u[7].z, u[6].z);
  *(uint4*)(d + (size_t)(cc + 2)*R + rr) = o;
  o.x = bfpack(u[1].w, u[0].w); o.y = bfpack(u[3].w, u[2].w);
  o.z = bfpack(u[5].w, u[4].w); o.w = bfpack(u[7].w, u[6].w);
  *(uint4*)(d + (size_t)(cc + 3)*R + rr) = o;
}

// ---------------- softmax + bias + top-4 + row scatter + tokslot/zwbuf ----------------
// R11 restructure: out-write moved to combine_kernel. topk emits per token:
// tokslot[t][k] = assignment slot (e*ECAP+pos) or -1 for zero-experts; zwbuf[t] = zw.
__global__ __launch_bounds__(256) void topk_kernel(
    const float* __restrict__ logits, const float* __restrict__ bias,
    int* __restrict__ cursors, int* __restrict__ rowmap, float* __restrict__ roww,
    int* __restrict__ tokslot, float* __restrict__ zwbuf){
  const int tid = threadIdx.x;
  if (tid < 8){
    const int t = blockIdx.x * 8 + tid;
    float sc[32], bsc[32];
    #pragma unroll
    for (int i = 0; i < 32; i += 4){
      float4 v = *(const float4*)(logits + (size_t)t*NSLOT + i);
      sc[i] = v.x; sc[i+1] = v.y; sc[i+2] = v.z; sc[i+3] = v.w;
    }
    float mx = sc[0];
    #pragma unroll
    for (int i = 1; i < 32; ++i) mx = fmaxf(mx, sc[i]);
    float sum = 0.f;
    #pragma unroll
    for (int i = 0; i < 32; ++i){ sc[i] = __expf(sc[i]-mx); sum += sc[i]; }
    float inv = 1.f / sum;
    #pragma unroll
    for (int i = 0; i < 32; ++i){ sc[i] *= inv; bsc[i] = sc[i] + bias[i]; }
    unsigned int chosen = 0;
    float zw = 0.f;
    #pragma unroll
    for (int k = 0; k < TOPK; ++k){
      float bv = -1e30f, bw = 0.f; int best = 0;
      #pragma unroll
      for (int i = 0; i < 32; ++i){
        float v = ((chosen >> i) & 1u) ? -1e30f : bsc[i];
        if (v > bv){ bv = v; best = i; bw = sc[i]; }
      }
      chosen |= (1u << best);
      int slot = -1;
      if (best < NE){
        int pos = atomicAdd(&cursors[best], 1);
        rowmap[best*ECAP + pos] = t;
        roww[best*ECAP + pos]   = bw;
        slot = best*ECAP + pos;
      } else zw += bw;
      tokslot[t*TOPK + k] = slot;
    }
    zwbuf[t] = zw;
  }
}

// Map linear tile -> (expert, row-base e*ECAP, rows ne, m0). False if out of range.
static __device__ __forceinline__ bool tile_map(const int* __restrict__ counts, int tile,
                                                int& e, int& off, int& ne, int& m0){
  int cumT = 0; e = -1; ne = 0; m0 = 0;
  #pragma unroll
  for (int ee = 0; ee < NE; ++ee){
    int c = counts[ee];
    int nt = (c + 127) >> 7;
    bool here = (e < 0) && (tile < cumT + nt);
    if (here){ e = ee; ne = c; m0 = (tile - cumT) * 128; }
    cumT += nt;
  }
  off = (e >= 0) ? e * ECAP : 0;
  return e >= 0;
}

// ---------------- fused gate+up GEMM + SwiGLU (128x128, TRIPLE-buf, glds) ----------------
// R12 post-mortem: grid ~256 blocks = 1 block/CU = 1 wave/SIMD; the 2-barrier K-loop with
// 1-deep prefetch exposes (load_latency - 155cy MFMA) of stall per K-step -> MfmaUtil 16%.
// M-split (R11) was null: pipeline DEPTH, not block count, is the binder. Fix: 2-deep
// prefetch (3 LDS buffers, 74KB): stage tiles 0,1 in prologue; at iter k issue tile k+2,
// WAIT_VM(12) (= 2 tiles x 6 loads in flight, counted-vmcnt). No layout/addressing change.
__global__ __launch_bounds__(256, 2) void gateup_kernel(
    const unsigned short* __restrict__ xb,
    const unsigned short* __restrict__ wgb,
    const unsigned short* __restrict__ wub,
    const int* __restrict__ counts,
    const int* __restrict__ rowmap,
    const float* __restrict__ roww,
    unsigned short* __restrict__ act){
  const int b = blockIdx.x;
  int e, off, ne, m0;
  if (!tile_map(counts, b >> 2, e, off, ne, m0)) return;
  const int n0 = (b & 3) * 128;

  __shared__ unsigned short sA [3][128*32];
  __shared__ unsigned short sBg[3][128*32];
  __shared__ unsigned short sBu[3][128*32];
  __shared__ int sT[128];

  const int tid = threadIdx.x, lane = tid & 63, wid = tid >> 6;
  if (tid < 128){ int r = m0 + tid; sT[tid] = rowmap[off + ((r < ne) ? r : 0)]; }
  __syncthreads();

  const int r_in = lane >> 2, seg = lane & 3;
  const int rt0 = wid*32 + r_in, rt1 = rt0 + 16;
  const size_t wbase = (size_t)e * Id * Hd;

  const unsigned short* pA0 = xb + (size_t)sT[rt0]*Hd + seg*8;
  const unsigned short* pA1 = xb + (size_t)sT[rt1]*Hd + seg*8;
  const unsigned short* pG0 = wgb + wbase + (size_t)(n0+rt0)*Hd + seg*8;
  const unsigned short* pG1 = wgb + wbase + (size_t)(n0+rt1)*Hd + seg*8;
  const unsigned short* pU0 = wub + wbase + (size_t)(n0+rt0)*Hd + seg*8;
  const unsigned short* pU1 = wub + wbase + (size_t)(n0+rt1)*Hd + seg*8;
  const int dA0 = wid*1024, dA1 = wid*1024 + 512;

  floatx4 accg[4][4], accu[4][4];
  #pragma unroll
  for (int i = 0; i < 4; ++i)
    #pragma unroll
    for (int j = 0; j < 4; ++j){
      floatx4 z = {0.f,0.f,0.f,0.f};
      accg[i][j] = z; accu[i][j] = z;
    }
  const int wm = (wid & 1) * 64, wn = (wid >> 1) * 64;
  const int fm = lane & 15, fq = lane >> 4;

  // prologue: stage tiles 0 and 1
  load_lds16(pA0, &sA[0][dA0]);       load_lds16(pA1, &sA[0][dA1]);
  load_lds16(pG0, &sBg[0][dA0]);      load_lds16(pG1, &sBg[0][dA1]);
  load_lds16(pU0, &sBu[0][dA0]);      load_lds16(pU1, &sBu[0][dA1]);
  load_lds16(pA0 + 32, &sA[1][dA0]);  load_lds16(pA1 + 32, &sA[1][dA1]);
  load_lds16(pG0 + 32, &sBg[1][dA0]); load_lds16(pG1 + 32, &sBg[1][dA1]);
  load_lds16(pU0 + 32, &sBu[1][dA0]); load_lds16(pU1 + 32, &sBu[1][dA1]);

  int cur = 0;
  #pragma unroll 2
  for (int kit = 0; kit < 32; ++kit){
    if (kit < 30){
      const int nb = (cur >= 1) ? cur - 1 : 2;   // (kit+2) % 3
      const int nk = (kit + 2) * 32;
      load_lds16(pA0 + nk, &sA[nb][dA0]);  load_lds16(pA1 + nk, &sA[nb][dA1]);
      load_lds16(pG0 + nk, &sBg[nb][dA0]); load_lds16(pG1 + nk, &sBg[nb][dA1]);
      load_lds16(pU0 + nk, &sBu[nb][dA0]); load_lds16(pU1 + nk, &sBu[nb][dA1]);
      WAIT_VM(12);                               // tiles kit+1, kit+2 may stay in flight
    } else if (kit == 30){
      WAIT_VM(6);                                // tile 31 may stay in flight
    } else {
      WAIT_VM(0);
    }
    wg_barrier();
    bf16x8 av[4], bgv[4], buv[4];
    #pragma unroll
    for (int i = 0; i < 4; ++i)
      av[i] = *(const bf16x8*)(&sA[cur][(wm + i*16 + fm)*32 + fq*8]);
    #pragma unroll
    for (int j = 0; j < 4; ++j){
      bgv[j] = *(const bf16x8*)(&sBg[cur][(wn + j*16 + fm)*32 + fq*8]);
      buv[j] = *(const bf16x8*)(&sBu[cur][(wn + j*16 + fm)*32 + fq*8]);
    }
    #pragma unroll
    for (int i = 0; i < 4; ++i)
      #pragma unroll
      for (int j = 0; j < 4; ++j){
        accg[i][j] = __builtin_amdgcn_mfma_f32_16x16x32_bf16(av[i], bgv[j], accg[i][j], 0, 0, 0);
        accu[i][j] = __builtin_amdgcn_mfma_f32_16x16x32_bf16(av[i], buv[j], accu[i][j], 0, 0, 0);
      }
    wg_barrier();
    cur = (cur == 2) ? 0 : cur + 1;
  }

  #pragma unroll
  for (int i = 0; i < 4; ++i){
    #pragma unroll
    for (int r = 0; r < 4; ++r){
      int row = wm + i*16 + fq*4 + r;
      if (m0 + row < ne){
        float w = roww[off + m0 + row];
        size_t rb = (size_t)(off + m0 + row) * Id + n0;
        #pragma unroll
        for (int j = 0; j < 4; ++j){
          float g = accg[i][j][r];
          float u = accu[i][j][r];
          float a = (g / (1.f + __expf(-g))) * u * w;
          act[rb + wn + j*16 + fm] = f2bf(a);
        }
      }
    }
  }
}

// ---------------- down GEMM -> plain bf16 partial-row stores (no atomics) ----------------
// R5/R8/R11 triangulation: down was ATOMIC-RMW bound. R12 fix (plain stores into
// partials + combine gather) dropped it out of the top-5. Unchanged this round.
__global__ __launch_bounds__(256, 4) void down_kernel(
    const unsigned short* __restrict__ act,
    const unsigned short* __restrict__ wdb,
    const int* __restrict__ counts,
    unsigned short* __restrict__ partials){
  const int b = blockIdx.x;
  int e, off, ne, m0;
  if (!tile_map(counts, b >> 3, e, off, ne, m0)) return;
  const int n0 = (b & 7) * 128;

  __shared__ unsigned short sA[2][128*32];
  __shared__ unsigned short sB[2][128*32];

  const int tid = threadIdx.x, lane = tid & 63, wid = tid >> 6;

  const int r_in = lane >> 2, seg = lane & 3;
  const int rt0 = wid*32 + r_in, rt1 = rt0 + 16;
  const int gr0 = off + ((m0 + rt0 < ne) ? (m0 + rt0) : 0);
  const int gr1 = off + ((m0 + rt1 < ne) ? (m0 + rt1) : 0);
  const size_t wbase = (size_t)e * Hd * Id;
  const unsigned short* pA0 = act + (size_t)gr0*Id + seg*8;
  const unsigned short* pA1 = act + (size_t)gr1*Id + seg*8;
  const unsigned short* pB0 = wdb + wbase + (size_t)(n0+rt0)*Id + seg*8;
  const unsigned short* pB1 = wdb + wbase + (size_t)(n0+rt1)*Id + seg*8;
  const int dA0 = wid*1024, dA1 = wid*1024 + 512;

  floatx4 acc[4][4];
  #pragma unroll
  for (int i = 0; i < 4; ++i)
    #pragma unroll
    for (int j = 0; j < 4; ++j){ floatx4 z = {0.f,0.f,0.f,0.f}; acc[i][j] = z; }
  const int wm = (wid & 1) * 64, wn = (wid >> 1) * 64;
  const int fm = lane & 15, fq = lane >> 4;

  load_lds16(pA0, &sA[0][dA0]); load_lds16(pA1, &sA[0][dA1]);
  load_lds16(pB0, &sB[0][dA0]); load_lds16(pB1, &sB[0][dA1]);

  #pragma unroll 2
  for (int kit = 0; kit < 16; ++kit){
    const int cur = kit & 1;
    if (kit < 15){
      const int nk = (kit+1)*32;
      const int nb = 1 - cur;
      load_lds16(pA0 + nk, &sA[nb][dA0]); load_lds16(pA1 + nk, &sA[nb][dA1]);
      load_lds16(pB0 + nk, &sB[nb][dA0]); load_lds16(pB1 + nk, &sB[nb][dA1]);
      WAIT_VM(4);
    } else {
      WAIT_VM(0);
    }
    wg_barrier();
    bf16x8 av[4], bv[4];
    #pragma unroll
    for (int i = 0; i < 4; ++i) av[i] = *(const bf16x8*)(&sA[cur][(wm + i*16 + fm)*32 + fq*8]);
    #pragma unroll
    for (int j = 0; j < 4; ++j) bv[j] = *(const bf16x8*)(&sB[cur][(wn + j*16 + fm)*32 + fq*8]);
    #pragma unroll
    for (int i = 0; i < 4; ++i)
      #pragma unroll
      for (int j = 0; j < 4; ++j)
        acc[i][j] = __builtin_amdgcn_mfma_f32_16x16x32_bf16(av[i], bv[j], acc[i][j], 0, 0, 0);
    wg_barrier();
  }

  #pragma unroll
  for (int i = 0; i < 4; ++i){
    #pragma unroll
    for (int r = 0; r < 4; ++r){
      int row = wm + i*16 + fq*4 + r;
      if (m0 + row < ne){
        size_t pb = (size_t)(off + m0 + row) * Hd + n0;
        #pragma unroll
        for (int j = 0; j < 4; ++j)
          partials[pb + wn + j*16 + fm] = f2bf(acc[i][j][r]);
      }
    }
  }
}

// ---------------- combine: out[t] = zw*x[t] + sum_k partials[slot_k] ----------------
// Pure coalesced streaming (~50 MB): replaces the atomic scatter entirely.
__global__ __launch_bounds__(256) void combine_kernel(
    const float* __restrict__ x, const unsigned short* __restrict__ partials,
    const int* __restrict__ tokslot, const float* __restrict__ zwbuf,
    float* __restrict__ out){
  const int tid = threadIdx.x;
  const int t0 = blockIdx.x * 4;
  const int c4 = tid * 4;
  #pragma unroll
  for (int r = 0; r < 4; ++r){
    const int t = t0 + r;
    const float zw = zwbuf[t];
    const int s0 = tokslot[t*TOPK + 0], s1 = tokslot[t*TOPK + 1];
    const int s2 = tokslot[t*TOPK + 2], s3 = tokslot[t*TOPK + 3];
    float4 xv = *(const float4*)(x + (size_t)t*Hd + c4);
    float4 o;
    o.x = zw*xv.x; o.y = zw*xv.y; o.z = zw*xv.z; o.w = zw*xv.w;
    if (s0 >= 0){
      ushort4 p = *(const ushort4*)(partials + (size_t)s0*Hd + c4);
      o.x += bf2f(p.x); o.y += bf2f(p.y); o.z += bf2f(p.z); o.w += bf2f(p.w);
    }
    if (s1 >= 0){
      ushort4 p = *(const ushort4*)(partials + (size_t)s1*Hd + c4);
      o.x += bf2f(p.x); o.y += bf2f(p.y); o.z += bf2f(p.z); o.w += bf2f(p.w);
    }
    if (s2 >= 0){
      ushort4 p = *(const ushort4*)(partials + (size_t)s2*Hd + c4);
      o.x += bf2f(p.x); o.y += bf2f(p.y); o.z += bf2f(p.z); o.w += bf2f(p.w);
    }
    if (s3 >= 0){
      ushort4 p = *(const ushort4*)(partials + (size_t)s3*Hd + c4);
      o.x += bf2f(p.x); o.y += bf2f(p.y); o.z += bf2f(p.z); o.w += bf2f(p.w);
    }
    *(float4*)(out + (size_t)t*Hd + c4) = o;
  }
}

// =================================================================
extern "C" void kernel_launch(void* const* d_in, const int* in_sizes, int n_in,
                              void* d_out, int out_size, void* d_ws, size_t ws_size,
                              hipStream_t stream){
  (void)in_sizes; (void)n_in; (void)out_size; (void)ws_size;
  const float* x    = (const float*)d_in[0];
  const float* rw   = (const float*)d_in[1];
  const float* bias = (const float*)d_in[2];
  const float* wg   = (const float*)d_in[3];
  const float* wu   = (const float*)d_in[4];
  const float* wd   = (const float*)d_in[5];
  float* out = (float*)d_out;

  char* ws = (char*)d_ws;
  const size_t WSZ = (size_t)NE * Id * Hd * 2;
  unsigned short* wgb = (unsigned short*)(ws);
  unsigned short* wub = (unsigned short*)(ws + WSZ);
  unsigned short* wdb = (unsigned short*)(ws + 2*WSZ);
  unsigned short* xb  = (unsigned short*)(ws + 3*WSZ);
  unsigned short* act = (unsigned short*)(ws + 3*WSZ + (size_t)T_TOK*Hd*2);
  char* misc = ws + 3*WSZ + (size_t)T_TOK*Hd*2 + (size_t)NE*ECAP*Id*2;

  // partials[NE*ECAP][Hd] bf16 = 32 MB: aliases wgb+wub (dead after gateup).
  unsigned short* partials = (unsigned short*)(ws);

  const size_t LOGB = (size_t)T_TOK * NSLOT * 4;
  float* logits  = (float*)misc;
  int*   cursors = (int*)(misc + LOGB);
  char* p2 = misc + LOGB + 256;
  int*   rowmap  = (int*)p2;                    p2 += (size_t)NE*ECAP*4;
  float* roww    = (float*)p2;                  p2 += (size_t)NE*ECAP*4;
  int*   tokslot = (int*)p2;                    p2 += (size_t)T_TOK*TOPK*4;
  float* zwbuf   = (float*)p2;

  router_kernel<<<T_TOK/8, 256, 0, stream>>>(x, rw, xb, logits, cursors);
  transpose_kernel<<<3072, 256, 0, stream>>>(wg, wu, wd, wgb, wub, wdb);
  topk_kernel<<<T_TOK/8, 256, 0, stream>>>(logits, bias, cursors, rowmap, roww,
                                           tokslot, zwbuf);
  gateup_kernel<<<MAXT*4, 256, 0, stream>>>(xb, wgb, wub, cursors, rowmap, roww, act);
  down_kernel<<<MAXT*8, 256, 0, stream>>>(act, wdb, cursors, partials);
  combine_kernel<<<T_TOK/4, 256, 0, stream>>>(x, partials, tokslot, zwbuf, out);
}

// Round 14
// 264.308 us; speedup vs baseline: 1.0251x; 1.0251x over previous
//
#include <hip/hip_runtime.h>
#include <stdint.h>

#define T_TOK 4096
#define Hd    1024
#define Id    512
#define NE    16
#define NSLOT 32
#define TOPK  4
#define ECAP  1024
#define MAXT  (NE * (ECAP/128))

typedef __bf16 bf16x8 __attribute__((ext_vector_type(8)));
typedef float  floatx4 __attribute__((ext_vector_type(4)));

#define WAIT_VM(n) asm volatile("s_waitcnt vmcnt(" #n ")" ::: "memory")

static __device__ __forceinline__ void wg_barrier(){
  asm volatile("" ::: "memory");
  __builtin_amdgcn_s_barrier();
  asm volatile("" ::: "memory");
}

static __device__ __forceinline__ unsigned short f2bf(float f){
  unsigned int u = __float_as_uint(f);
  u = u + 0x7fffu + ((u >> 16) & 1u);
  return (unsigned short)(u >> 16);
}

static __device__ __forceinline__ float bf2f(unsigned short u){
  return __uint_as_float((unsigned int)u << 16);
}

// bf16(hi_src) << 16 | bf16(lo_src), truncation rounding (hi halves via v_perm)
static __device__ __forceinline__ uint32_t bfpack(uint32_t hi_src, uint32_t lo_src){
  return __builtin_amdgcn_perm(hi_src, lo_src, 0x07060302u);
}

static __device__ __forceinline__ void load_lds16(const void* g, void* l){
  __builtin_amdgcn_global_load_lds((const __attribute__((address_space(1))) void*)g,
                                   (__attribute__((address_space(3))) void*)l, 16, 0, 0);
}

// ---------------- router: logits (8 tok x 8 slots per wave) + fused x->bf16 --------------
// R4: wave-per-token was latency-bound; 8tok x 8slot amortizes rw. R10: do NOT fuse with
// transpose (zero overlap, 140 VGPR coupling).
__global__ __launch_bounds__(256) void router_kernel(
    const float* __restrict__ x, const float* __restrict__ rw,
    unsigned short* __restrict__ xb, float* __restrict__ logits,
    int* __restrict__ cursors){
  const int tid = threadIdx.x;
  if (blockIdx.x == 0 && tid < NE) cursors[tid] = 0;
  const int lane = tid & 63, sg = tid >> 6;       // sg = slot group 0..3
  const int t0 = blockIdx.x * 8;
  const int l4 = lane * 4;

  float v[64];                                     // v[t*8+s], s within group
  #pragma unroll
  for (int i = 0; i < 64; ++i) v[i] = 0.f;

  #pragma unroll
  for (int c = 0; c < 4; ++c){
    const int h = c * 256 + l4;
    float4 xv[8];
    #pragma unroll
    for (int t = 0; t < 8; ++t)
      xv[t] = *(const float4*)(x + (size_t)(t0 + t) * Hd + h);
    if (sg == 0){
      #pragma unroll
      for (int t = 0; t < 8; ++t){
        ushort4 o;
        o.x = f2bf(xv[t].x); o.y = f2bf(xv[t].y);
        o.z = f2bf(xv[t].z); o.w = f2bf(xv[t].w);
        *(ushort4*)(xb + (size_t)(t0 + t) * Hd + h) = o;
      }
    }
    #pragma unroll
    for (int s = 0; s < 8; ++s){
      float4 rv = *(const float4*)(rw + (size_t)(sg * 8 + s) * Hd + h);
      #pragma unroll
      for (int t = 0; t < 8; ++t)
        v[t*8 + s] += xv[t].x*rv.x + xv[t].y*rv.y + xv[t].z*rv.z + xv[t].w*rv.w;
    }
  }

  // merging butterfly: after bit `off`, v[i] (i % 2off == 0) holds value
  // (i | (lane & (2off-1))) summed over lane-groups of size 2off.
  #pragma unroll
  for (int off = 1; off < 64; off <<= 1){
    #pragma unroll
    for (int i = 0; i < 64; i += 2*off){
      const int j = i + off;
      float send  = (lane & off) ? v[i] : v[j];
      float other = __shfl_xor(send, off);
      v[i] = ((lane & off) ? v[j] : v[i]) + other;
    }
  }
  // v[0] on lane l = full sum of flat index l: t = l>>3, s = l&7
  logits[(size_t)(t0 + (lane >> 3)) * NSLOT + sg * 8 + (lane & 7)] = v[0];
}

// ---------------- weight transpose: register-only 128x64 tiles ----------------
// At its streaming plateau (~3.3 TB/s logical; R9 store-widening was a null; rate is
// occupancy- and pattern-insensitive). Do not iterate further.
__global__ __launch_bounds__(256) void transpose_kernel(
    const float* __restrict__ wg, const float* __restrict__ wu,
    const float* __restrict__ wd,
    unsigned short* __restrict__ wgb, unsigned short* __restrict__ wub,
    unsigned short* __restrict__ wdb){
  const int tb = blockIdx.x;                // 0..3071
  const int tid = threadIdx.x;
  const float* src; unsigned short* dst; int R, C, rt, ct;
  const int arr = tb >> 10;                 // 0:wg 1:wu 2:wd (1024 tiles each)
  const int rem = tb & 1023;
  const int e  = rem >> 6;                  // 64 tiles/expert
  const int t2 = rem & 63;
  if (arr == 0)      { src = wg; dst = wgb; R = Hd; C = Id; rt = t2 >> 3; ct = t2 & 7;  }
  else if (arr == 1) { src = wu; dst = wub; R = Hd; C = Id; rt = t2 >> 3; ct = t2 & 7;  }
  else               { src = wd; dst = wdb; R = Id; C = Hd; rt = t2 >> 4; ct = t2 & 15; }
  const int r0 = rt * 128, c0 = ct * 64;
  const float* s = src + (size_t)e * R * C;
  unsigned short* d = dst + (size_t)e * R * C;
  const int r_idx = tid >> 4;               // 16 r-blocks x 8 rows = 128 rows
  const int c_idx = tid & 15;               // 16 c-blocks x 4 cols = 64 cols
  const int rr = r0 + r_idx * 8;
  const int cc = c0 + c_idx * 4;
  uint4 u[8];
  #pragma unroll
  for (int p = 0; p < 8; ++p)
    u[p] = *(const uint4*)(s + (size_t)(rr + p)*C + cc);
  uint4 o;
  o.x = bfpack(u[1].x, u[0].x); o.y = bfpack(u[3].x, u[2].x);
  o.z = bfpack(u[5].x, u[4].x); o.w = bfpack(u[7].x, u[6].x);
  *(uint4*)(d + (size_t)(cc + 0)*R + rr) = o;
  o.x = bfpack(u[1].y, u[0].y); o.y = bfpack(u[3].y, u[2].y);
  o.z = bfpack(u[5].y, u[4].y); o.w = bfpack(u[7].y, u[6].y);
  *(uint4*)(d + (size_t)(cc + 1)*R + rr) = o;
  o.x = bfpack(u[1].z, u[0].z); o.y = bfpack(u[3].z, u[2].z);
  o.z = bfpack(u[5].z, u[4].z); o.w = bfpack(u[7].z, u[6].z);
  *(uint4*)(d + (size_t)(cc + 2)*R + rr) = o;
  o.x = bfpack(u[1].w, u[0].w); o.y = bfpack(u[3].w, u[2].w);
  o.z = bfpack(u[5].w, u[4].w); o.w = bfpack(u[7].w, u[6].w);
  *(uint4*)(d + (size_t)(cc + 3)*R + rr) = o;
}

// ---------------- softmax + bias + top-4 + row scatter + tokslot/zwbuf ----------------
// R11 restructure: out-write moved to combine_kernel. topk emits per token:
// tokslot[t][k] = assignment slot (e*ECAP+pos) or -1 for zero-experts; zwbuf[t] = zw.
__global__ __launch_bounds__(256) void topk_kernel(
    const float* __restrict__ logits, const float* __restrict__ bias,
    int* __restrict__ cursors, int* __restrict__ rowmap, float* __restrict__ roww,
    int* __restrict__ tokslot, float* __restrict__ zwbuf){
  const int tid = threadIdx.x;
  if (tid < 8){
    const int t = blockIdx.x * 8 + tid;
    float sc[32], bsc[32];
    #pragma unroll
    for (int i = 0; i < 32; i += 4){
      float4 v = *(const float4*)(logits + (size_t)t*NSLOT + i);
      sc[i] = v.x; sc[i+1] = v.y; sc[i+2] = v.z; sc[i+3] = v.w;
    }
    float mx = sc[0];
    #pragma unroll
    for (int i = 1; i < 32; ++i) mx = fmaxf(mx, sc[i]);
    float sum = 0.f;
    #pragma unroll
    for (int i = 0; i < 32; ++i){ sc[i] = __expf(sc[i]-mx); sum += sc[i]; }
    float inv = 1.f / sum;
    #pragma unroll
    for (int i = 0; i < 32; ++i){ sc[i] *= inv; bsc[i] = sc[i] + bias[i]; }
    unsigned int chosen = 0;
    float zw = 0.f;
    #pragma unroll
    for (int k = 0; k < TOPK; ++k){
      float bv = -1e30f, bw = 0.f; int best = 0;
      #pragma unroll
      for (int i = 0; i < 32; ++i){
        float v = ((chosen >> i) & 1u) ? -1e30f : bsc[i];
        if (v > bv){ bv = v; best = i; bw = sc[i]; }
      }
      chosen |= (1u << best);
      int slot = -1;
      if (best < NE){
        int pos = atomicAdd(&cursors[best], 1);
        rowmap[best*ECAP + pos] = t;
        roww[best*ECAP + pos]   = bw;
        slot = best*ECAP + pos;
      } else zw += bw;
      tokslot[t*TOPK + k] = slot;
    }
    zwbuf[t] = zw;
  }
}

// Map linear tile -> (expert, row-base e*ECAP, rows ne, m0). False if out of range.
static __device__ __forceinline__ bool tile_map(const int* __restrict__ counts, int tile,
                                                int& e, int& off, int& ne, int& m0){
  int cumT = 0; e = -1; ne = 0; m0 = 0;
  #pragma unroll
  for (int ee = 0; ee < NE; ++ee){
    int c = counts[ee];
    int nt = (c + 127) >> 7;
    bool here = (e < 0) && (tile < cumT + nt);
    if (here){ e = ee; ne = c; m0 = (tile - cumT) * 128; }
    cumT += nt;
  }
  off = (e >= 0) ? e * ECAP : 0;
  return e >= 0;
}

// ---------------- fused gate+up GEMM + SwiGLU (128x64 tiles, dbuf, glds) ----------------
// R13 post-mortem: triple-buffer was NULL (MfmaUtil 15.6% both ways) -> not prefetch-depth
// bound. The binder is the GRID: ~256 active blocks = 1 block/CU = 1 wave/SIMD; the serial
// ds_read->MFMA->barrier chain latency (~2500 cy/iter exposed) has no co-resident wave to
// hide it. Fix: N-split 128->64 => ~512 blocks = 2 blocks/CU = 2 waves/SIMD. Only the tiny
// A-panel (128 rows x 2KB, L2-resident) is re-read 2x; B traffic unchanged. LDS 32KB,
// 4 loads/thread-iter (WAIT_VM(4)), 16 MFMAs/wave-iter (acc[4][2] x2).
__global__ __launch_bounds__(256, 2) void gateup_kernel(
    const unsigned short* __restrict__ xb,
    const unsigned short* __restrict__ wgb,
    const unsigned short* __restrict__ wub,
    const int* __restrict__ counts,
    const int* __restrict__ rowmap,
    const float* __restrict__ roww,
    unsigned short* __restrict__ act){
  const int b = blockIdx.x;
  int e, off, ne, m0;
  if (!tile_map(counts, b >> 3, e, off, ne, m0)) return;
  const int n0 = (b & 7) * 64;

  __shared__ unsigned short sA [2][128*32];
  __shared__ unsigned short sBg[2][64*32];
  __shared__ unsigned short sBu[2][64*32];
  __shared__ int sT[128];

  const int tid = threadIdx.x, lane = tid & 63, wid = tid >> 6;
  if (tid < 128){ int r = m0 + tid; sT[tid] = rowmap[off + ((r < ne) ? r : 0)]; }
  __syncthreads();

  const int r_in = lane >> 2, seg = lane & 3;
  const int rt0 = wid*32 + r_in, rt1 = rt0 + 16;  // A: 128 rows, 2 loads/thread
  const int rtB = wid*16 + r_in;                  // B: 64 rows, 1 load/thread each
  const size_t wbase = (size_t)e * Id * Hd;

  const unsigned short* pA0 = xb + (size_t)sT[rt0]*Hd + seg*8;
  const unsigned short* pA1 = xb + (size_t)sT[rt1]*Hd + seg*8;
  const unsigned short* pG0 = wgb + wbase + (size_t)(n0+rtB)*Hd + seg*8;
  const unsigned short* pU0 = wub + wbase + (size_t)(n0+rtB)*Hd + seg*8;
  const int dA0 = wid*1024, dA1 = wid*1024 + 512;
  const int dB0 = wid*512;

  floatx4 accg[4][2], accu[4][2];
  #pragma unroll
  for (int i = 0; i < 4; ++i)
    #pragma unroll
    for (int j = 0; j < 2; ++j){
      floatx4 z = {0.f,0.f,0.f,0.f};
      accg[i][j] = z; accu[i][j] = z;
    }
  const int wm = (wid & 1) * 64, wn = (wid >> 1) * 32;
  const int fm = lane & 15, fq = lane >> 4;

  load_lds16(pA0, &sA[0][dA0]); load_lds16(pA1, &sA[0][dA1]);
  load_lds16(pG0, &sBg[0][dB0]);
  load_lds16(pU0, &sBu[0][dB0]);

  #pragma unroll 2
  for (int kit = 0; kit < 32; ++kit){
    const int cur = kit & 1;
    if (kit < 31){
      const int nk = (kit+1)*32;
      const int nb = 1 - cur;
      load_lds16(pA0 + nk, &sA[nb][dA0]); load_lds16(pA1 + nk, &sA[nb][dA1]);
      load_lds16(pG0 + nk, &sBg[nb][dB0]);
      load_lds16(pU0 + nk, &sBu[nb][dB0]);
      WAIT_VM(4);
    } else {
      WAIT_VM(0);
    }
    wg_barrier();
    bf16x8 av[4], bgv[2], buv[2];
    #pragma unroll
    for (int i = 0; i < 4; ++i)
      av[i] = *(const bf16x8*)(&sA[cur][(wm + i*16 + fm)*32 + fq*8]);
    #pragma unroll
    for (int j = 0; j < 2; ++j){
      bgv[j] = *(const bf16x8*)(&sBg[cur][(wn + j*16 + fm)*32 + fq*8]);
      buv[j] = *(const bf16x8*)(&sBu[cur][(wn + j*16 + fm)*32 + fq*8]);
    }
    #pragma unroll
    for (int i = 0; i < 4; ++i)
      #pragma unroll
      for (int j = 0; j < 2; ++j){
        accg[i][j] = __builtin_amdgcn_mfma_f32_16x16x32_bf16(av[i], bgv[j], accg[i][j], 0, 0, 0);
        accu[i][j] = __builtin_amdgcn_mfma_f32_16x16x32_bf16(av[i], buv[j], accu[i][j], 0, 0, 0);
      }
    wg_barrier();
  }

  #pragma unroll
  for (int i = 0; i < 4; ++i){
    #pragma unroll
    for (int r = 0; r < 4; ++r){
      int row = wm + i*16 + fq*4 + r;
      if (m0 + row < ne){
        float w = roww[off + m0 + row];
        size_t rb = (size_t)(off + m0 + row) * Id + n0;
        #pragma unroll
        for (int j = 0; j < 2; ++j){
          float g = accg[i][j][r];
          float u = accu[i][j][r];
          float a = (g / (1.f + __expf(-g))) * u * w;
          act[rb + wn + j*16 + fm] = f2bf(a);
        }
      }
    }
  }
}

// ---------------- down GEMM -> plain bf16 partial-row stores (no atomics) ----------------
// R5/R8/R11 triangulation: down was ATOMIC-RMW bound. R12 fix (plain stores into
// partials + combine gather) dropped it out of the top-5. Unchanged.
__global__ __launch_bounds__(256, 4) void down_kernel(
    const unsigned short* __restrict__ act,
    const unsigned short* __restrict__ wdb,
    const int* __restrict__ counts,
    unsigned short* __restrict__ partials){
  const int b = blockIdx.x;
  int e, off, ne, m0;
  if (!tile_map(counts, b >> 3, e, off, ne, m0)) return;
  const int n0 = (b & 7) * 128;

  __shared__ unsigned short sA[2][128*32];
  __shared__ unsigned short sB[2][128*32];

  const int tid = threadIdx.x, lane = tid & 63, wid = tid >> 6;

  const int r_in = lane >> 2, seg = lane & 3;
  const int rt0 = wid*32 + r_in, rt1 = rt0 + 16;
  const int gr0 = off + ((m0 + rt0 < ne) ? (m0 + rt0) : 0);
  const int gr1 = off + ((m0 + rt1 < ne) ? (m0 + rt1) : 0);
  const size_t wbase = (size_t)e * Hd * Id;
  const unsigned short* pA0 = act + (size_t)gr0*Id + seg*8;
  const unsigned short* pA1 = act + (size_t)gr1*Id + seg*8;
  const unsigned short* pB0 = wdb + wbase + (size_t)(n0+rt0)*Id + seg*8;
  const unsigned short* pB1 = wdb + wbase + (size_t)(n0+rt1)*Id + seg*8;
  const int dA0 = wid*1024, dA1 = wid*1024 + 512;

  floatx4 acc[4][4];
  #pragma unroll
  for (int i = 0; i < 4; ++i)
    #pragma unroll
    for (int j = 0; j < 4; ++j){ floatx4 z = {0.f,0.f,0.f,0.f}; acc[i][j] = z; }
  const int wm = (wid & 1) * 64, wn = (wid >> 1) * 64;
  const int fm = lane & 15, fq = lane >> 4;

  load_lds16(pA0, &sA[0][dA0]); load_lds16(pA1, &sA[0][dA1]);
  load_lds16(pB0, &sB[0][dA0]); load_lds16(pB1, &sB[0][dA1]);

  #pragma unroll 2
  for (int kit = 0; kit < 16; ++kit){
    const int cur = kit & 1;
    if (kit < 15){
      const int nk = (kit+1)*32;
      const int nb = 1 - cur;
      load_lds16(pA0 + nk, &sA[nb][dA0]); load_lds16(pA1 + nk, &sA[nb][dA1]);
      load_lds16(pB0 + nk, &sB[nb][dA0]); load_lds16(pB1 + nk, &sB[nb][dA1]);
      WAIT_VM(4);
    } else {
      WAIT_VM(0);
    }
    wg_barrier();
    bf16x8 av[4], bv[4];
    #pragma unroll
    for (int i = 0; i < 4; ++i) av[i] = *(const bf16x8*)(&sA[cur][(wm + i*16 + fm)*32 + fq*8]);
    #pragma unroll
    for (int j = 0; j < 4; ++j) bv[j] = *(const bf16x8*)(&sB[cur][(wn + j*16 + fm)*32 + fq*8]);
    #pragma unroll
    for (int i = 0; i < 4; ++i)
      #pragma unroll
      for (int j = 0; j < 4; ++j)
        acc[i][j] = __builtin_amdgcn_mfma_f32_16x16x32_bf16(av[i], bv[j], acc[i][j], 0, 0, 0);
    wg_barrier();
  }

  #pragma unroll
  for (int i = 0; i < 4; ++i){
    #pragma unroll
    for (int r = 0; r < 4; ++r){
      int row = wm + i*16 + fq*4 + r;
      if (m0 + row < ne){
        size_t pb = (size_t)(off + m0 + row) * Hd + n0;
        #pragma unroll
        for (int j = 0; j < 4; ++j)
          partials[pb + wn + j*16 + fm] = f2bf(acc[i][j][r]);
      }
    }
  }
}

// ---------------- combine: out[t] = zw*x[t] + sum_k partials[slot_k] ----------------
// Pure coalesced streaming (~50 MB): replaces the atomic scatter entirely.
__global__ __launch_bounds__(256) void combine_kernel(
    const float* __restrict__ x, const unsigned short* __restrict__ partials,
    const int* __restrict__ tokslot, const float* __restrict__ zwbuf,
    float* __restrict__ out){
  const int tid = threadIdx.x;
  const int t0 = blockIdx.x * 4;
  const int c4 = tid * 4;
  #pragma unroll
  for (int r = 0; r < 4; ++r){
    const int t = t0 + r;
    const float zw = zwbuf[t];
    const int s0 = tokslot[t*TOPK + 0], s1 = tokslot[t*TOPK + 1];
    const int s2 = tokslot[t*TOPK + 2], s3 = tokslot[t*TOPK + 3];
    float4 xv = *(const float4*)(x + (size_t)t*Hd + c4);
    float4 o;
    o.x = zw*xv.x; o.y = zw*xv.y; o.z = zw*xv.z; o.w = zw*xv.w;
    if (s0 >= 0){
      ushort4 p = *(const ushort4*)(partials + (size_t)s0*Hd + c4);
      o.x += bf2f(p.x); o.y += bf2f(p.y); o.z += bf2f(p.z); o.w += bf2f(p.w);
    }
    if (s1 >= 0){
      ushort4 p = *(const ushort4*)(partials + (size_t)s1*Hd + c4);
      o.x += bf2f(p.x); o.y += bf2f(p.y); o.z += bf2f(p.z); o.w += bf2f(p.w);
    }
    if (s2 >= 0){
      ushort4 p = *(const ushort4*)(partials + (size_t)s2*Hd + c4);
      o.x += bf2f(p.x); o.y += bf2f(p.y); o.z += bf2f(p.z); o.w += bf2f(p.w);
    }
    if (s3 >= 0){
      ushort4 p = *(const ushort4*)(partials + (size_t)s3*Hd + c4);
      o.x += bf2f(p.x); o.y += bf2f(p.y); o.z += bf2f(p.z); o.w += bf2f(p.w);
    }
    *(float4*)(out + (size_t)t*Hd + c4) = o;
  }
}

// =================================================================
extern "C" void kernel_launch(void* const* d_in, const int* in_sizes, int n_in,
                              void* d_out, int out_size, void* d_ws, size_t ws_size,
                              hipStream_t stream){
  (void)in_sizes; (void)n_in; (void)out_size; (void)ws_size;
  const float* x    = (const float*)d_in[0];
  const float* rw   = (const float*)d_in[1];
  const float* bias = (const float*)d_in[2];
  const float* wg   = (const float*)d_in[3];
  const float* wu   = (const float*)d_in[4];
  const float* wd   = (const float*)d_in[5];
  float* out = (float*)d_out;

  char* ws = (char*)d_ws;
  const size_t WSZ = (size_t)NE * Id * Hd * 2;
  unsigned short* wgb = (unsigned short*)(ws);
  unsigned short* wub = (unsigned short*)(ws + WSZ);
  unsigned short* wdb = (unsigned short*)(ws + 2*WSZ);
  unsigned short* xb  = (unsigned short*)(ws + 3*WSZ);
  unsigned short* act = (unsigned short*)(ws + 3*WSZ + (size_t)T_TOK*Hd*2);
  char* misc = ws + 3*WSZ + (size_t)T_TOK*Hd*2 + (size_t)NE*ECAP*Id*2;

  // partials[NE*ECAP][Hd] bf16 = 32 MB: aliases wgb+wub (dead after gateup).
  unsigned short* partials = (unsigned short*)(ws);

  const size_t LOGB = (size_t)T_TOK * NSLOT * 4;
  float* logits  = (float*)misc;
  int*   cursors = (int*)(misc + LOGB);
  char* p2 = misc + LOGB + 256;
  int*   rowmap  = (int*)p2;                    p2 += (size_t)NE*ECAP*4;
  float* roww    = (float*)p2;                  p2 += (size_t)NE*ECAP*4;
  int*   tokslot = (int*)p2;                    p2 += (size_t)T_TOK*TOPK*4;
  float* zwbuf   = (float*)p2;

  router_kernel<<<T_TOK/8, 256, 0, stream>>>(x, rw, xb, logits, cursors);
  transpose_kernel<<<3072, 256, 0, stream>>>(wg, wu, wd, wgb, wub, wdb);
  topk_kernel<<<T_TOK/8, 256, 0, stream>>>(logits, bias, cursors, rowmap, roww,
                                           tokslot, zwbuf);
  gateup_kernel<<<MAXT*8, 256, 0, stream>>>(xb, wgb, wub, cursors, rowmap, roww, act);
  down_kernel<<<MAXT*8, 256, 0, stream>>>(act, wdb, cursors, partials);
  combine_kernel<<<T_TOK/4, 256, 0, stream>>>(x, partials, tokslot, zwbuf, out);
}